// Round 15
// baseline (381.133 us; speedup 1.0000x reference)
//
#include <hip/hip_runtime.h>
#include <stdint.h>

#define B_ 4
#define L_ 4096
#define D_ 1024
#define C_ 2048
#define M_ (B_ * L_)  // 16384
#define LCH 16        // conv l-chunk per block

typedef __attribute__((ext_vector_type(8))) short s16x8;
typedef __attribute__((ext_vector_type(4))) float fx4;
typedef __attribute__((ext_vector_type(4))) unsigned int ux4;
typedef unsigned short bfu;  // bf16 bits

__device__ __forceinline__ float bits2f(short s) {
  return __uint_as_float(((uint32_t)(unsigned short)s) << 16);
}
__device__ __forceinline__ bfu f2bf(float f) {
  uint32_t u = __float_as_uint(f);
  uint32_t r = (u + 0x7FFFu + ((u >> 16) & 1u)) >> 16;  // RNE
  return (bfu)r;
}
__device__ __forceinline__ uint32_t pk_bf16(float lo, float hi) {
  uint32_t r;
  asm("v_cvt_pk_bf16_f32 %0, %1, %2" : "=v"(r) : "v"(lo), "v"(hi));
  return r;
}

__device__ __forceinline__ void gload_lds16(const void* g, void* l) {
  __builtin_amdgcn_global_load_lds(
      (const __attribute__((address_space(1))) void*)g,
      (__attribute__((address_space(3))) void*)l, 16, 0, 0);
}

#define BAR() asm volatile("s_barrier" ::: "memory")
#define LGKM0() asm volatile("s_waitcnt lgkmcnt(0)" ::: "memory")
#define VMW14() asm volatile("s_waitcnt vmcnt(14)" ::: "memory")
#define VMW12() asm volatile("s_waitcnt vmcnt(12)" ::: "memory")
#define VMW10() asm volatile("s_waitcnt vmcnt(10)" ::: "memory")
#define VMW8() asm volatile("s_waitcnt vmcnt(8)" ::: "memory")
#define VMW4() asm volatile("s_waitcnt vmcnt(4)" ::: "memory")
#define VMW2() asm volatile("s_waitcnt vmcnt(2)" ::: "memory")
#define VMW0() asm volatile("s_waitcnt vmcnt(0)" ::: "memory")

// ---------------- transpose + fp32->bf16 convert: out[c][r] = in[r][c] ----------------
template <int R, int CC>
__global__ __launch_bounds__(256) void transpose_cvt(const float* __restrict__ in,
                                                     bfu* __restrict__ out) {
  __shared__ float tile[32][33];
  const int bx = blockIdx.x, by = blockIdx.y, tx = threadIdx.x;
  for (int j = threadIdx.y; j < 32; j += 8)
    tile[j][tx] = in[(size_t)(by * 32 + j) * CC + bx * 32 + tx];
  __syncthreads();
  for (int j = threadIdx.y; j < 32; j += 8)
    out[(size_t)(bx * 32 + j) * R + by * 32 + tx] = f2bf(tile[tx][j]);
}

// =================== shared GEMM pieces (R11 structure) ===================
// LDS bytes: buf0 { A-kh0 @0, A-kh1 @16384, B-kh0 @32768, B-kh1 @49152 };
// buf1 = +65536.  Rows 64 B.  Swizzle involution (both sides): XOR byte bits 4-5
// with row bits 1-2 (0 conflicts, R4 PMC).

template <int KD>
__device__ __forceinline__ void stage_half(const bfu* __restrict__ Mt, int r0, int kb,
                                           bfu* region, int t) {
#pragma unroll
  for (int h = 0; h < 2; h++) {
    const int u = t + h * 512;
    const int srow = u >> 2;
    const int sslot = (u & 3) ^ ((srow >> 1) & 3);
    gload_lds16(Mt + (size_t)(r0 + srow) * KD + kb + sslot * 8, region + u * 8);
  }
}

#define LF2(p, off) (*reinterpret_cast<const s16x8*>((p) + (off)))

#define MFMA16(ACCROW)                                                                 \
  __builtin_amdgcn_s_setprio(1);                                                       \
  _Pragma("unroll") for (int m = 0; m < 4; m++) _Pragma("unroll")                      \
      for (int n = 0; n < 4; n++) ACCROW =                                             \
          __builtin_amdgcn_mfma_f32_16x16x32_bf16(af[m], bf4[n], ACCROW, 0, 0, 0);     \
  __builtin_amdgcn_s_setprio(0);

// ---------------- plain 256x256 GEMM (GEMM2; R11 proven) ----------------
#define KTILE(PA_, PB_, CBEL, NBEL, tu)                                                \
  {                                                                                    \
    s16x8 af[4], bf4[4];                                                               \
    _Pragma("unroll") for (int m = 0; m < 4; m++) af[m] = LF2(PA_, m * 1024);          \
    _Pragma("unroll") for (int n = 0; n < 4; n++) bf4[n] = LF2(PB_, n * 1024);         \
    if ((tu) + 1 < ntk) stage_half<KD>(A, row0, ((tu) + 1) * 64 + 32, (NBEL) + 8192, t);\
    BAR();                                                                             \
    LGKM0();                                                                           \
    MFMA16(acc[m][n])                                                                  \
    BAR();                                                                             \
    _Pragma("unroll") for (int m = 0; m < 4; m++) af[m] = LF2(PA_, 4096 + m * 1024);   \
    if ((tu) + 1 < ntk) stage_half<KD>(Bt, col0, ((tu) + 1) * 64 + 32, (NBEL) + 24576, t);\
    BAR();                                                                             \
    LGKM0();                                                                           \
    MFMA16(acc[m + 4][n])                                                              \
    if ((tu) < ntk - 1) VMW8();                                                        \
    else VMW0();                                                                       \
    BAR();                                                                             \
    _Pragma("unroll") for (int m = 0; m < 4; m++) af[m] = LF2(PA_, 16384 + m * 1024);  \
    _Pragma("unroll") for (int n = 0; n < 4; n++) bf4[n] = LF2(PB_, 16384 + n * 1024); \
    if ((tu) + 2 < ntk) stage_half<KD>(A, row0, ((tu) + 2) * 64, (CBEL) + 0, t);       \
    BAR();                                                                             \
    LGKM0();                                                                           \
    MFMA16(acc[m][n])                                                                  \
    BAR();                                                                             \
    _Pragma("unroll") for (int m = 0; m < 4; m++) af[m] =                              \
        LF2(PA_, 16384 + 4096 + m * 1024);                                             \
    if ((tu) + 2 < ntk) stage_half<KD>(Bt, col0, ((tu) + 2) * 64, (CBEL) + 16384, t);  \
    BAR();                                                                             \
    LGKM0();                                                                           \
    MFMA16(acc[m + 4][n])                                                              \
    if ((tu) < ntk - 2) VMW8();                                                        \
    else if ((tu) == ntk - 2) VMW4();                                                  \
    BAR();                                                                             \
  }

template <int MM, int N, int KD, bool OUT_BF16>
__global__ __launch_bounds__(512, 2) void gemm256(const bfu* __restrict__ A,
                                                  const bfu* __restrict__ Bt,
                                                  const float* __restrict__ bias,
                                                  void* __restrict__ Cptr) {
  __shared__ bfu lds[2 * 4 * 8192];  // 128 KiB
  const int t = threadIdx.x;
  const int lane = t & 63, wid = t >> 6;
  const int wr = wid >> 2, wc = wid & 3;
  const int lr = lane & 15, lg = lane >> 4;
  const int cpx = gridDim.x >> 3;
  const int li = (blockIdx.x & 7) * cpx + (blockIdx.x >> 3);
  const int row0 = (li % (MM / 256)) * 256;
  const int col0 = (li / (MM / 256)) * 256;
  constexpr int ntk = KD / 64;
  const int abase = ((wr * 128 + lr) * 64 + lg * 16) ^ (((lr >> 1) & 3) << 4);
  const int bbase = ((wc * 64 + lr) * 64 + lg * 16) ^ (((lr >> 1) & 3) << 4);

  char* const lb = reinterpret_cast<char*>(lds);
  const char* const pA0 = lb + abase;
  const char* const pA1 = lb + 65536 + abase;
  const char* const pB0 = lb + 32768 + bbase;
  const char* const pB1 = lb + 65536 + 32768 + bbase;

  fx4 acc[8][4] = {};

  stage_half<KD>(A, row0, 0, lds + 0, t);
  stage_half<KD>(Bt, col0, 0, lds + 16384, t);
  stage_half<KD>(A, row0, 32, lds + 8192, t);
  stage_half<KD>(Bt, col0, 32, lds + 24576, t);
  stage_half<KD>(A, row0, 64, lds + 32768 + 0, t);
  stage_half<KD>(Bt, col0, 64, lds + 32768 + 16384, t);
  VMW8();
  BAR();

  for (int tau2 = 0; tau2 < ntk; tau2 += 2) {
    KTILE(pA0, pB0, lds, lds + 32768, tau2);
    KTILE(pA1, pB1, lds + 32768, lds, tau2 + 1);
  }

  float bv[4];
#pragma unroll
  for (int n = 0; n < 4; n++) bv[n] = bias[col0 + wc * 64 + n * 16 + lr];
#pragma unroll
  for (int m = 0; m < 8; m++)
#pragma unroll
    for (int n = 0; n < 4; n++)
#pragma unroll
      for (int r = 0; r < 4; r++) {
        const int row = row0 + wr * 128 + m * 16 + lg * 4 + r;
        const int col = col0 + wc * 64 + n * 16 + lr;
        const float v = acc[m][n][r] + bv[n];
        if constexpr (OUT_BF16)
          ((bfu*)Cptr)[(size_t)row * N + col] = f2bf(v);
        else
          ((float*)Cptr)[(size_t)row * N + col] = v;
      }
}

// ---------------- GEMM1 with fused fp32->bf16 A-staging (R15) ----------------
// AL(arr,TILE): 8 coalesced fp32 dwordx4 loads of A-tile TILE (both k-halves)
// into registers — same row/slot mapping as stage_half (inverse swizzle on
// source, linear LDS dest).  AW(arr,NBEL): cvt_pk + 4 ds_write_b128, linear
// chunks (conflict-free).  AL(t+2) issued at P1(t); AW(t+1) at P4(t).
// vmcnt ledger (FIFO): W1@P2 = 12/4/0; P4 pre-AW = 10/2; end-P4 wait removed.

#define ALOAD(arr, TILE)                                                               \
  {                                                                                    \
    _Pragma("unroll") for (int kh = 0; kh < 2; kh++)                                   \
    _Pragma("unroll") for (int c = 0; c < 2; c++) {                                    \
      const float* p_ = Ax + (size_t)(row0 + (t >> 2) + c * 128) * KD + (TILE)*64 +    \
                        kh * 32 + sslot * 8;                                           \
      arr[kh * 4 + c * 2 + 0] = *(const fx4*)p_;                                       \
      arr[kh * 4 + c * 2 + 1] = *(const fx4*)(p_ + 4);                                 \
    }                                                                                  \
  }

#define AWRITE(arr, NBEL)                                                              \
  {                                                                                    \
    _Pragma("unroll") for (int kh = 0; kh < 2; kh++)                                   \
    _Pragma("unroll") for (int c = 0; c < 2; c++) {                                    \
      ux4 w_;                                                                          \
      const fx4 fa_ = arr[kh * 4 + c * 2], fb_ = arr[kh * 4 + c * 2 + 1];              \
      w_[0] = pk_bf16(fa_[0], fa_[1]);                                                 \
      w_[1] = pk_bf16(fa_[2], fa_[3]);                                                 \
      w_[2] = pk_bf16(fb_[0], fb_[1]);                                                 \
      w_[3] = pk_bf16(fb_[2], fb_[3]);                                                 \
      *reinterpret_cast<ux4*>((NBEL) + kh * 8192 + ((size_t)t + c * 512) * 8) = w_;    \
    }                                                                                  \
  }

#define KTA(PA_, PB_, CBEL, NBEL, tu, FILL, CONS)                                      \
  {                                                                                    \
    s16x8 af[4], bf4[4];                                                               \
    /* P1: kh0 m0-3 | issue AL(tu+2) */                                                \
    _Pragma("unroll") for (int m = 0; m < 4; m++) af[m] = LF2(PA_, m * 1024);          \
    _Pragma("unroll") for (int n = 0; n < 4; n++) bf4[n] = LF2(PB_, n * 1024);         \
    if ((tu) + 2 < ntk) ALOAD(FILL, (tu) + 2);                                         \
    BAR();                                                                             \
    LGKM0();                                                                           \
    MFMA16(acc[m][n])                                                                  \
    BAR();                                                                             \
    /* P2: kh0 m4-7 | stage B-kh1(tu+1) | W1 */                                        \
    _Pragma("unroll") for (int m = 0; m < 4; m++) af[m] = LF2(PA_, 4096 + m * 1024);   \
    if ((tu) + 1 < ntk) stage_half<KD>(Bt, col0, ((tu) + 1) * 64 + 32, (NBEL) + 24576, t);\
    BAR();                                                                             \
    LGKM0();                                                                           \
    MFMA16(acc[m + 4][n])                                                              \
    if ((tu) < ntk - 2) VMW12();                                                       \
    else if ((tu) == ntk - 2) VMW4();                                                  \
    else VMW0();                                                                       \
    BAR();                                                                             \
    /* P3: kh1 m0-3 */                                                                 \
    _Pragma("unroll") for (int m = 0; m < 4; m++) af[m] = LF2(PA_, 16384 + m * 1024);  \
    _Pragma("unroll") for (int n = 0; n < 4; n++) bf4[n] = LF2(PB_, 16384 + n * 1024); \
    BAR();                                                                             \
    LGKM0();                                                                           \
    MFMA16(acc[m][n])                                                                  \
    BAR();                                                                             \
    /* P4: kh1 m4-7 | AW(tu+1) | stage B-kh0(tu+2) */                                  \
    _Pragma("unroll") for (int m = 0; m < 4; m++) af[m] =                              \
        LF2(PA_, 16384 + 4096 + m * 1024);                                             \
    if ((tu) + 1 < ntk) {                                                              \
      if ((tu) < ntk - 2) VMW10();                                                     \
      else VMW2();                                                                     \
      AWRITE(CONS, NBEL);                                                              \
    }                                                                                  \
    if ((tu) + 2 < ntk) stage_half<KD>(Bt, col0, ((tu) + 2) * 64, (CBEL) + 16384, t);  \
    BAR();                                                                             \
    LGKM0();                                                                           \
    MFMA16(acc[m + 4][n])                                                              \
    BAR();                                                                             \
  }

template <int MM, int N, int KD>
__global__ __launch_bounds__(512, 2) void gemm256_acvt(const float* __restrict__ Ax,
                                                       const bfu* __restrict__ Bt,
                                                       const float* __restrict__ bias,
                                                       bfu* __restrict__ Cptr) {
  __shared__ bfu lds[2 * 4 * 8192];  // 128 KiB
  const int t = threadIdx.x;
  const int lane = t & 63, wid = t >> 6;
  const int wr = wid >> 2, wc = wid & 3;
  const int lr = lane & 15, lg = lane >> 4;
  const int cpx = gridDim.x >> 3;
  const int li = (blockIdx.x & 7) * cpx + (blockIdx.x >> 3);
  const int row0 = (li % (MM / 256)) * 256;
  const int col0 = (li / (MM / 256)) * 256;
  constexpr int ntk = KD / 64;
  const int abase = ((wr * 128 + lr) * 64 + lg * 16) ^ (((lr >> 1) & 3) << 4);
  const int bbase = ((wc * 64 + lr) * 64 + lg * 16) ^ (((lr >> 1) & 3) << 4);
  const int sslot = (t & 3) ^ ((t >> 3) & 3);

  char* const lb = reinterpret_cast<char*>(lds);
  const char* const pA0 = lb + abase;
  const char* const pA1 = lb + 65536 + abase;
  const char* const pB0 = lb + 32768 + bbase;
  const char* const pB1 = lb + 65536 + 32768 + bbase;

  fx4 acc[8][4] = {};
  fx4 aE[8], aO[8];

  // prologue: AL(0)->aE, AL(1)->aO (16 loads); B t0k0,t0k1,t1k0 (6 gloads);
  // VMW14 (drain AL0; leave AL1+B6); AW(0)->buf0; VMW4 (drain t0k0; leave
  // t0k1+t1k0); LGKM0; BAR.
  ALOAD(aE, 0);
  ALOAD(aO, 1);
  stage_half<KD>(Bt, col0, 0, lds + 16384, t);
  stage_half<KD>(Bt, col0, 32, lds + 24576, t);
  stage_half<KD>(Bt, col0, 64, lds + 32768 + 16384, t);
  VMW14();
  AWRITE(aE, lds);
  VMW4();
  LGKM0();
  BAR();

  for (int tau2 = 0; tau2 < ntk; tau2 += 2) {
    KTA(pA0, pB0, lds, lds + 32768, tau2, aE, aO);
    KTA(pA1, pB1, lds + 32768, lds, tau2 + 1, aO, aE);
  }

  // epilogue: C/D layout col=lane&15, row=(lane>>4)*4+reg
  float bv[4];
#pragma unroll
  for (int n = 0; n < 4; n++) bv[n] = bias[col0 + wc * 64 + n * 16 + lr];
#pragma unroll
  for (int m = 0; m < 8; m++)
#pragma unroll
    for (int n = 0; n < 4; n++)
#pragma unroll
      for (int r = 0; r < 4; r++) {
        const int row = row0 + wr * 128 + m * 16 + lg * 4 + r;
        const int col = col0 + wc * 64 + n * 16 + lr;
        Cptr[(size_t)row * N + col] = f2bf(acc[m][n][r] + bv[n]);
      }
}

// ---------------- depthwise causal conv K=4, sliding window ----------------
__global__ __launch_bounds__(256) void dwconv_slide(const bfu* __restrict__ xe,
                                                    const float* __restrict__ cw,
                                                    const float* __restrict__ cb,
                                                    bfu* __restrict__ y) {
  const int nchunk = L_ / LCH;
  const int b = blockIdx.x / nchunk;
  const int l0 = (blockIdx.x % nchunk) * LCH;
  const int cg = threadIdx.x << 3;

  float w[4][8], bias8[8];
#pragma unroll
  for (int tt = 0; tt < 4; tt++) {
    fx4 w0 = *(const fx4*)(cw + tt * C_ + cg);
    fx4 w1 = *(const fx4*)(cw + tt * C_ + cg + 4);
#pragma unroll
    for (int i = 0; i < 4; i++) {
      w[tt][i] = w0[i];
      w[tt][i + 4] = w1[i];
    }
  }
  {
    fx4 c0 = *(const fx4*)(cb + cg), c1 = *(const fx4*)(cb + cg + 4);
#pragma unroll
    for (int i = 0; i < 4; i++) {
      bias8[i] = c0[i];
      bias8[i + 4] = c1[i];
    }
  }

  const size_t base = ((size_t)b * L_ + l0) * C_ + cg;
  s16x8 h0 = {}, h1 = {}, h2 = {};
  if (l0 != 0) {
    h0 = *reinterpret_cast<const s16x8*>(xe + base - 3 * C_);
    h1 = *reinterpret_cast<const s16x8*>(xe + base - 2 * C_);
    h2 = *reinterpret_cast<const s16x8*>(xe + base - 1 * C_);
  }
#pragma unroll
  for (int i = 0; i < LCH; i++) {
    s16x8 h3 = *reinterpret_cast<const s16x8*>(xe + base + (size_t)i * C_);
    s16x8 o;
#pragma unroll
    for (int j = 0; j < 8; j++) {
      float v = bias8[j];
      v = fmaf(bits2f(h0[j]), w[0][j], v);
      v = fmaf(bits2f(h1[j]), w[1][j], v);
      v = fmaf(bits2f(h2[j]), w[2][j], v);
      v = fmaf(bits2f(h3[j]), w[3][j], v);
      o[j] = (short)f2bf(v);
    }
    *reinterpret_cast<s16x8*>(y + base + (size_t)i * C_) = o;
    h0 = h1;
    h1 = h2;
    h2 = h3;
  }
}

extern "C" void kernel_launch(void* const* d_in, const int* in_sizes, int n_in,
                              void* d_out, int out_size, void* d_ws, size_t ws_size,
                              hipStream_t stream) {
  const float* x = (const float*)d_in[0];
  const float* W_exp = (const float*)d_in[1];
  const float* b_exp = (const float*)d_in[2];
  const float* cw = (const float*)d_in[3];
  const float* cb = (const float*)d_in[4];
  const float* W_cmp = (const float*)d_in[5];
  const float* b_cmp = (const float*)d_in[6];
  float* out = (float*)d_out;

  char* ws = (char*)d_ws;
  bfu* wexp_t = (bfu*)(ws);                // [C][D] bf16, 4 MiB
  bfu* wcmp_t = (bfu*)(ws + (4u << 20));   // [D][C] bf16, 4 MiB
  bfu* xe = (bfu*)(ws + (8u << 20));       // [M][C] bf16, 64 MiB
  bfu* y = (bfu*)(ws + (72u << 20));       // [M][C] bf16, 64 MiB

  transpose_cvt<D_, C_><<<dim3(C_ / 32, D_ / 32), dim3(32, 8), 0, stream>>>(W_exp, wexp_t);
  transpose_cvt<C_, D_><<<dim3(D_ / 32, C_ / 32), dim3(32, 8), 0, stream>>>(W_cmp, wcmp_t);
  // expand GEMM with fused fp32->bf16 A-staging: xe = x @ W_exp + b_exp
  gemm256_acvt<M_, C_, D_><<<512, 512, 0, stream>>>(x, wexp_t, b_exp, xe);
  // conv
  dwconv_slide<<<B_ * (L_ / LCH), 256, 0, stream>>>(xe, cw, cb, y);
  // compress GEMM: out = y @ W_cmp + b_cmp
  gemm256<M_, D_, C_, false><<<256, 512, 0, stream>>>(y, wcmp_t, b_cmp, out);
}

// Round 16
// 200.974 us; speedup vs baseline: 1.8964x; 1.8964x over previous
//
#include <hip/hip_runtime.h>
#include <stdint.h>

#define B_ 4
#define L_ 4096
#define D_ 1024
#define C_ 2048
#define M_ (B_ * L_)  // 16384
#define LCH 16        // conv l-chunk per block

typedef __attribute__((ext_vector_type(8))) short s16x8;
typedef __attribute__((ext_vector_type(4))) float fx4;
typedef unsigned short bfu;  // bf16 bits

__device__ __forceinline__ float bits2f(short s) {
  return __uint_as_float(((uint32_t)(unsigned short)s) << 16);
}
__device__ __forceinline__ bfu f2bf(float f) {
  uint32_t u = __float_as_uint(f);
  uint32_t r = (u + 0x7FFFu + ((u >> 16) & 1u)) >> 16;  // RNE
  return (bfu)r;
}

__device__ __forceinline__ void gload_lds16(const void* g, void* l) {
  __builtin_amdgcn_global_load_lds(
      (const __attribute__((address_space(1))) void*)g,
      (__attribute__((address_space(3))) void*)l, 16, 0, 0);
}

#define BAR() asm volatile("s_barrier" ::: "memory")
#define LGKM0() asm volatile("s_waitcnt lgkmcnt(0)" ::: "memory")
#define VMW8() asm volatile("s_waitcnt vmcnt(8)" ::: "memory")
#define VMW4() asm volatile("s_waitcnt vmcnt(4)" ::: "memory")
#define VMW0() asm volatile("s_waitcnt vmcnt(0)" ::: "memory")

// ---------------- fp32 -> bf16 bulk convert ----------------
__global__ __launch_bounds__(256) void cvt_f32_bf16(const float* __restrict__ in,
                                                    bfu* __restrict__ out, int n8) {
  const int stride = gridDim.x * blockDim.x;
  for (int i = blockIdx.x * blockDim.x + threadIdx.x; i < n8; i += stride) {
    const size_t off = (size_t)i * 8;
    fx4 a = *(const fx4*)(in + off);
    fx4 b = *(const fx4*)(in + off + 4);
    s16x8 o;
#pragma unroll
    for (int j = 0; j < 4; j++) {
      o[j] = (short)f2bf(a[j]);
      o[j + 4] = (short)f2bf(b[j]);
    }
    *reinterpret_cast<s16x8*>(out + off) = o;
  }
}

// ---------------- transpose + fp32->bf16 convert: out[c][r] = in[r][c] ----------------
template <int R, int CC>
__global__ __launch_bounds__(256) void transpose_cvt(const float* __restrict__ in,
                                                     bfu* __restrict__ out) {
  __shared__ float tile[32][33];
  const int bx = blockIdx.x, by = blockIdx.y, tx = threadIdx.x;
  for (int j = threadIdx.y; j < 32; j += 8)
    tile[j][tx] = in[(size_t)(by * 32 + j) * CC + bx * 32 + tx];
  __syncthreads();
  for (int j = threadIdx.y; j < 32; j += 8)
    out[(size_t)(bx * 32 + j) * R + by * 32 + tx] = f2bf(tile[tx][j]);
}

// =================== 256x256 8-phase GEMM (R11 — session best) ===================
// LDS bytes: buf0 { A-kh0 @0, A-kh1 @16384, B-kh0 @32768, B-kh1 @49152 };
// buf1 = +65536.  Rows 64 B.  Swizzle involution (both sides): XOR byte bits 4-5
// with row bits 1-2 (0 conflicts, R4 PMC).  Counted vmcnt: 8 loads (4 half-tiles)
// permanently in flight; waits only touch >=4-phase-old loads.

template <int KD>
__device__ __forceinline__ void stage_half(const bfu* __restrict__ Mt, int r0, int kb,
                                           bfu* region, int t) {
#pragma unroll
  for (int h = 0; h < 2; h++) {
    const int u = t + h * 512;
    const int srow = u >> 2;
    const int sslot = (u & 3) ^ ((srow >> 1) & 3);
    gload_lds16(Mt + (size_t)(r0 + srow) * KD + kb + sslot * 8, region + u * 8);
  }
}

#define LF2(p, off) (*reinterpret_cast<const s16x8*>((p) + (off)))

#define KTILE(PA_, PB_, CBEL, NBEL, tu)                                                \
  {                                                                                    \
    s16x8 af[4], bf4[4];                                                               \
    /* P1: kh0 rows 0-63 x n0-3 | stage (tu+1).A-kh1 */                                \
    _Pragma("unroll") for (int m = 0; m < 4; m++) af[m] = LF2(PA_, m * 1024);          \
    _Pragma("unroll") for (int n = 0; n < 4; n++) bf4[n] = LF2(PB_, n * 1024);         \
    if ((tu) + 1 < ntk) stage_half<KD>(A, row0, ((tu) + 1) * 64 + 32, (NBEL) + 8192, t);\
    BAR();                                                                             \
    LGKM0();                                                                           \
    __builtin_amdgcn_s_setprio(1);                                                     \
    _Pragma("unroll") for (int m = 0; m < 4; m++) _Pragma("unroll")                    \
        for (int n = 0; n < 4; n++) acc[m][n] =                                        \
            __builtin_amdgcn_mfma_f32_16x16x32_bf16(af[m], bf4[n], acc[m][n], 0, 0, 0);\
    __builtin_amdgcn_s_setprio(0);                                                     \
    BAR();                                                                             \
    /* P2: kh0 rows 64-127 (reuse bf4) | stage (tu+1).B-kh1 | W1 */                    \
    _Pragma("unroll") for (int m = 0; m < 4; m++) af[m] = LF2(PA_, 4096 + m * 1024);   \
    if ((tu) + 1 < ntk) stage_half<KD>(Bt, col0, ((tu) + 1) * 64 + 32, (NBEL) + 24576, t);\
    BAR();                                                                             \
    LGKM0();                                                                           \
    __builtin_amdgcn_s_setprio(1);                                                     \
    _Pragma("unroll") for (int m = 0; m < 4; m++) _Pragma("unroll")                    \
        for (int n = 0; n < 4; n++) acc[m + 4][n] =                                    \
            __builtin_amdgcn_mfma_f32_16x16x32_bf16(af[m], bf4[n], acc[m + 4][n], 0, 0, 0);\
    __builtin_amdgcn_s_setprio(0);                                                     \
    if ((tu) < ntk - 1) VMW8();                                                        \
    else VMW0();                                                                       \
    BAR();                                                                             \
    /* P3: kh1 rows 0-63 x n0-3 | stage (tu+2).A-kh0 (kh0 dead after P2) */            \
    _Pragma("unroll") for (int m = 0; m < 4; m++) af[m] = LF2(PA_, 16384 + m * 1024);  \
    _Pragma("unroll") for (int n = 0; n < 4; n++) bf4[n] = LF2(PB_, 16384 + n * 1024); \
    if ((tu) + 2 < ntk) stage_half<KD>(A, row0, ((tu) + 2) * 64, (CBEL) + 0, t);       \
    BAR();                                                                             \
    LGKM0();                                                                           \
    __builtin_amdgcn_s_setprio(1);                                                     \
    _Pragma("unroll") for (int m = 0; m < 4; m++) _Pragma("unroll")                    \
        for (int n = 0; n < 4; n++) acc[m][n] =                                        \
            __builtin_amdgcn_mfma_f32_16x16x32_bf16(af[m], bf4[n], acc[m][n], 0, 0, 0);\
    __builtin_amdgcn_s_setprio(0);                                                     \
    BAR();                                                                             \
    /* P4: kh1 rows 64-127 | stage (tu+2).B-kh0 | W2 */                                \
    _Pragma("unroll") for (int m = 0; m < 4; m++) af[m] =                              \
        LF2(PA_, 16384 + 4096 + m * 1024);                                             \
    if ((tu) + 2 < ntk) stage_half<KD>(Bt, col0, ((tu) + 2) * 64, (CBEL) + 16384, t);  \
    BAR();                                                                             \
    LGKM0();                                                                           \
    __builtin_amdgcn_s_setprio(1);                                                     \
    _Pragma("unroll") for (int m = 0; m < 4; m++) _Pragma("unroll")                    \
        for (int n = 0; n < 4; n++) acc[m + 4][n] =                                    \
            __builtin_amdgcn_mfma_f32_16x16x32_bf16(af[m], bf4[n], acc[m + 4][n], 0, 0, 0);\
    __builtin_amdgcn_s_setprio(0);                                                     \
    if ((tu) < ntk - 2) VMW8();                                                        \
    else if ((tu) == ntk - 2) VMW4();                                                  \
    BAR();                                                                             \
  }

template <int MM, int N, int KD, bool OUT_BF16>
__global__ __launch_bounds__(512, 2) void gemm256(const bfu* __restrict__ A,
                                                  const bfu* __restrict__ Bt,
                                                  const float* __restrict__ bias,
                                                  void* __restrict__ Cptr) {
  __shared__ bfu lds[2 * 4 * 8192];  // 128 KiB
  const int t = threadIdx.x;
  const int lane = t & 63, wid = t >> 6;
  const int wr = wid >> 2, wc = wid & 3;
  const int lr = lane & 15, lg = lane >> 4;
  const int cpx = gridDim.x >> 3;
  const int li = (blockIdx.x & 7) * cpx + (blockIdx.x >> 3);
  const int row0 = (li % (MM / 256)) * 256;
  const int col0 = (li / (MM / 256)) * 256;
  constexpr int ntk = KD / 64;
  const int abase = ((wr * 128 + lr) * 64 + lg * 16) ^ (((lr >> 1) & 3) << 4);
  const int bbase = ((wc * 64 + lr) * 64 + lg * 16) ^ (((lr >> 1) & 3) << 4);

  char* const lb = reinterpret_cast<char*>(lds);
  const char* const pA0 = lb + abase;
  const char* const pA1 = lb + 65536 + abase;
  const char* const pB0 = lb + 32768 + bbase;
  const char* const pB1 = lb + 65536 + 32768 + bbase;

  fx4 acc[8][4] = {};

  // prologue: tile0 all 4 halves + tile1 kh0 halves = 12 loads; drain oldest 4.
  stage_half<KD>(A, row0, 0, lds + 0, t);
  stage_half<KD>(Bt, col0, 0, lds + 16384, t);
  stage_half<KD>(A, row0, 32, lds + 8192, t);
  stage_half<KD>(Bt, col0, 32, lds + 24576, t);
  stage_half<KD>(A, row0, 64, lds + 32768 + 0, t);
  stage_half<KD>(Bt, col0, 64, lds + 32768 + 16384, t);
  VMW8();
  BAR();

  for (int tau2 = 0; tau2 < ntk; tau2 += 2) {
    KTILE(pA0, pB0, lds, lds + 32768, tau2);
    KTILE(pA1, pB1, lds + 32768, lds, tau2 + 1);
  }

  // epilogue: C/D layout col=lane&15, row=(lane>>4)*4+reg
  float bv[4];
#pragma unroll
  for (int n = 0; n < 4; n++) bv[n] = bias[col0 + wc * 64 + n * 16 + lr];
#pragma unroll
  for (int m = 0; m < 8; m++)
#pragma unroll
    for (int n = 0; n < 4; n++)
#pragma unroll
      for (int r = 0; r < 4; r++) {
        const int row = row0 + wr * 128 + m * 16 + lg * 4 + r;
        const int col = col0 + wc * 64 + n * 16 + lr;
        const float v = acc[m][n][r] + bv[n];
        if constexpr (OUT_BF16)
          ((bfu*)Cptr)[(size_t)row * N + col] = f2bf(v);
        else
          ((float*)Cptr)[(size_t)row * N + col] = v;
      }
}

// ---------------- depthwise causal conv K=4, sliding window ----------------
__global__ __launch_bounds__(256) void dwconv_slide(const bfu* __restrict__ xe,
                                                    const float* __restrict__ cw,
                                                    const float* __restrict__ cb,
                                                    bfu* __restrict__ y) {
  const int nchunk = L_ / LCH;
  const int b = blockIdx.x / nchunk;
  const int l0 = (blockIdx.x % nchunk) * LCH;
  const int cg = threadIdx.x << 3;

  float w[4][8], bias8[8];
#pragma unroll
  for (int tt = 0; tt < 4; tt++) {
    fx4 w0 = *(const fx4*)(cw + tt * C_ + cg);
    fx4 w1 = *(const fx4*)(cw + tt * C_ + cg + 4);
#pragma unroll
    for (int i = 0; i < 4; i++) {
      w[tt][i] = w0[i];
      w[tt][i + 4] = w1[i];
    }
  }
  {
    fx4 c0 = *(const fx4*)(cb + cg), c1 = *(const fx4*)(cb + cg + 4);
#pragma unroll
    for (int i = 0; i < 4; i++) {
      bias8[i] = c0[i];
      bias8[i + 4] = c1[i];
    }
  }

  const size_t base = ((size_t)b * L_ + l0) * C_ + cg;
  s16x8 h0 = {}, h1 = {}, h2 = {};
  if (l0 != 0) {
    h0 = *reinterpret_cast<const s16x8*>(xe + base - 3 * C_);
    h1 = *reinterpret_cast<const s16x8*>(xe + base - 2 * C_);
    h2 = *reinterpret_cast<const s16x8*>(xe + base - 1 * C_);
  }
#pragma unroll
  for (int i = 0; i < LCH; i++) {
    s16x8 h3 = *reinterpret_cast<const s16x8*>(xe + base + (size_t)i * C_);
    s16x8 o;
#pragma unroll
    for (int j = 0; j < 8; j++) {
      float v = bias8[j];
      v = fmaf(bits2f(h0[j]), w[0][j], v);
      v = fmaf(bits2f(h1[j]), w[1][j], v);
      v = fmaf(bits2f(h2[j]), w[2][j], v);
      v = fmaf(bits2f(h3[j]), w[3][j], v);
      o[j] = (short)f2bf(v);
    }
    *reinterpret_cast<s16x8*>(y + base + (size_t)i * C_) = o;
    h0 = h1;
    h1 = h2;
    h2 = h3;
  }
}

extern "C" void kernel_launch(void* const* d_in, const int* in_sizes, int n_in,
                              void* d_out, int out_size, void* d_ws, size_t ws_size,
                              hipStream_t stream) {
  const float* x = (const float*)d_in[0];
  const float* W_exp = (const float*)d_in[1];
  const float* b_exp = (const float*)d_in[2];
  const float* cw = (const float*)d_in[3];
  const float* cb = (const float*)d_in[4];
  const float* W_cmp = (const float*)d_in[5];
  const float* b_cmp = (const float*)d_in[6];
  float* out = (float*)d_out;

  char* ws = (char*)d_ws;
  bfu* wexp_t = (bfu*)(ws);                // [C][D] bf16, 4 MiB
  bfu* wcmp_t = (bfu*)(ws + (4u << 20));   // [D][C] bf16, 4 MiB
  bfu* xb = (bfu*)(ws + (8u << 20));       // [M][D] bf16, 32 MiB
  bfu* xe = (bfu*)(ws + (40u << 20));      // [M][C] bf16, 64 MiB
  bfu* y = (bfu*)(ws + (104u << 20));      // [M][C] bf16, 64 MiB

  cvt_f32_bf16<<<2048, 256, 0, stream>>>(x, xb, M_ * D_ / 8);
  transpose_cvt<D_, C_><<<dim3(C_ / 32, D_ / 32), dim3(32, 8), 0, stream>>>(W_exp, wexp_t);
  transpose_cvt<C_, D_><<<dim3(D_ / 32, C_ / 32), dim3(32, 8), 0, stream>>>(W_cmp, wcmp_t);
  // expand GEMM: xe = x @ W_exp + b_exp
  gemm256<M_, C_, D_, true><<<512, 512, 0, stream>>>(xb, wexp_t, b_exp, xe);
  // conv
  dwconv_slide<<<B_ * (L_ / LCH), 256, 0, stream>>>(xe, cw, cb, y);
  // compress GEMM: out = y @ W_cmp + b_cmp
  gemm256<M_, D_, C_, false><<<256, 512, 0, stream>>>(y, wcmp_t, b_cmp, out);
}